// Round 6
// baseline (1358.071 us; speedup 1.0000x reference)
//
#include <hip/hip_runtime.h>
#include <cstdint>
#include <cstddef>

// Problem constants (match reference: B=64, L=512, STEPS=20)
#define LDIM 512
#define BATCH 64
#define NSTEPS 20
#define NTHREADS 256
#define PTHREADS 1024
#define SLABS 8              // 8 slabs of 64 rows per batch -> 512 blocks
#define CNT_STRIDE 16        // 64 B per counter: no line sharing across batches

using f4 = __attribute__((ext_vector_type(4))) float;
using h4 = __attribute__((ext_vector_type(4))) _Float16;

#define MU_MASKED (-1024.0f)   // exact in fp16; sentinel for M==0
#define MU_THRESH (-512.0f)

__device__ __forceinline__ float relu_f(float x) { return fmaxf(x, 0.0f); }
__device__ __forceinline__ float sign_f(float x) {
  return (x > 0.0f) ? 1.0f : ((x < 0.0f) ? -1.0f : 0.0f);
}
__device__ __forceinline__ float wave_reduce_sum(float v) {
  v += __shfl_xor(v, 32);
  v += __shfl_xor(v, 16);
  v += __shfl_xor(v, 8);
  v += __shfl_xor(v, 4);
  v += __shfl_xor(v, 2);
  v += __shfl_xor(v, 1);
  return v;
}
// Agent-scope RELAXED accesses: compile to sc1 (L1/L2-bypassing) ops serviced
// at the coherence point. Never acquire/threadfence here: agent-acquire emits
// buffer_inv (full per-XCD L2 invalidate) — round-1 spent 97% of time there.
__device__ __forceinline__ void st_agent(float* p, float v) {
  __hip_atomic_store(p, v, __ATOMIC_RELAXED, __HIP_MEMORY_SCOPE_AGENT);
}
__device__ __forceinline__ float ld_agent(const float* p) {
  return __hip_atomic_load(p, __ATOMIC_RELAXED, __HIP_MEMORY_SCOPE_AGENT);
}

// ---------------------------------------------------------------------------
// k_build: MU[b][i][j] = M_ij ? fp16(0.5*(sc_ij + sc_ji) - s) : -1024, via
// 64x64 tile pairs (coalesced transpose through LDS). Also zeroes the
// per-batch sync counters (flushed by the end-of-kernel release).
// Grid: BATCH * 36 tile pairs; 256 threads.
// ---------------------------------------------------------------------------
__global__ __launch_bounds__(NTHREADS) void k_build(
    const float* __restrict__ scores, const float* __restrict__ M,
    const float* __restrict__ s_ptr, _Float16* __restrict__ MU,
    unsigned int* __restrict__ counter) {
  __shared__ float Sa[64][65];
  __shared__ float Sb[64][65];
  if (blockIdx.x < BATCH && threadIdx.x == 0) counter[blockIdx.x * CNT_STRIDE] = 0u;
  const int b = blockIdx.x / 36;
  int rem = blockIdx.x % 36;
  int ti = 0;
  while (rem >= 8 - ti) {
    rem -= 8 - ti;
    ti++;
  }
  const int tj = ti + rem;
  const int tid = threadIdx.x;
  const int c = tid & 63;
  const int r0 = tid >> 6;
  const float sval = s_ptr[0];
  const size_t mb = (size_t)b * LDIM * LDIM;
#pragma unroll
  for (int k = 0; k < 16; k++) {
    const int r = 4 * k + r0;
    Sa[r][c] = scores[mb + (size_t)(ti * 64 + r) * LDIM + tj * 64 + c];
    Sb[r][c] = scores[mb + (size_t)(tj * 64 + r) * LDIM + ti * 64 + c];
  }
  __syncthreads();
#pragma unroll
  for (int k = 0; k < 16; k++) {
    const int r = 4 * k + r0;
    const size_t idx_ij = mb + (size_t)(ti * 64 + r) * LDIM + tj * 64 + c;
    const float mij = M[idx_ij];
    const float us = 0.5f * (Sa[r][c] + Sb[c][r]) - sval;
    MU[idx_ij] = (_Float16)((mij != 0.0f) ? us : MU_MASKED);
    if (ti != tj) {
      const size_t idx_ji = mb + (size_t)(tj * 64 + r) * LDIM + ti * 64 + c;
      const float mji = M[idx_ji];
      const float usj = 0.5f * (Sb[r][c] + Sa[c][r]) - sval;
      MU[idx_ji] = (_Float16)((mji != 0.0f) ? usj : MU_MASKED);
    }
  }
}

// ---------------------------------------------------------------------------
// k_persist: all 20 steps with A_hat resident on-chip; MU (fp16) streamed.
// ROUND-6 RE-TILE FOR LATENCY HIDING: round 5 proved the step loop is
// latency-bound (halving stream bytes left time unchanged, VALUBusy 19%,
// Occupancy 45%). Fix = 2x TLP: grid 512 blocks x 1024 threads, 2 blocks/CU
// (32 waves/CU). Block (b = blockIdx&63, sb = blockIdx>>6, SLABS=8) owns
// rows [sb*64, sb*64+64) of batch b. Per wave (16 waves): 4 rows — rows
// 0..2 in VGPRs (ahv[3][2] = 24 regs; 64-VGPR budget holds per rounds 2-5),
// row 3 in LDS ahL[16][512] (32 KB). LDS total 50 KB -> 2 blocks/CU.
// amdgpu_waves_per_eu(8) REQUIRES the <=64-VGPR allocation so 2-block/CU
// co-residency (and thus the plain-launch spin sync) is guaranteed.
// Plain launch only: cooperative launch measured ~175 us/replay of overhead
// (round 0 total-vs-dispatch gap 6 us with plain launches; rounds 2-5 gap
// ~175-260 us with cooperative). Grid == exact device capacity.
// Cross-block exchange per step: ~3 KB of partials via sc1 relaxed atomics +
// a monotonic per-batch arrival counter (8 arrivals/step). NO fences.
// ---------------------------------------------------------------------------
__global__ __launch_bounds__(PTHREADS)
__attribute__((amdgpu_waves_per_eu(8))) void k_persist(
    const float* __restrict__ scores, const _Float16* __restrict__ MU,
    const float* __restrict__ rho_p, const float* __restrict__ w_ptr,
    const float* __restrict__ alpha_ptr, const float* __restrict__ belt_ptr,
    const float* __restrict__ lra_ptr, const float* __restrict__ lrb_ptr,
    float* __restrict__ rowpart, float* __restrict__ colpart,
    unsigned int* __restrict__ counter, float* __restrict__ Ah) {
  __shared__ float ahL[16][LDIM];    // 32 KB: LDS-resident row 3 of each wave
  __shared__ float stage[8][LDIM];   // 16 KB: cross-wave col-sum staging
  __shared__ float lmsgS[LDIM];      // 2 KB   (total 50 KB -> 2 blocks/CU)

  const int tid = threadIdx.x;
  const int lane = tid & 63;
  const int w = tid >> 6;                  // 0..15
  const int b = blockIdx.x & (BATCH - 1);  // batch; %8 keeps siblings on 1 XCD
  const int sb = blockIdx.x >> 6;          // slab 0..7
  const int wrow = sb * 64 + w * 4;
  const int j0 = lane << 2;
  const size_t mb = (size_t)b * LDIM * LDIM;

  const float wv = w_ptr[0];
  const float belt = belt_ptr[0];
  const float lra = lra_ptr[0];
  const float lrb = lrb_ptr[0];
  float at = alpha_ptr[0];  // a_t = alpha * lra^sp, updated iteratively
  float lrbp = 1.0f;        // lrb^(sp-1) for sp>=1
  float lm_reg = 0.0f;      // Lm[tid] (valid for tid < LDIM)

  const size_t RP = (size_t)BATCH * LDIM;          // rowpart parity stride
  const size_t CP = (size_t)BATCH * SLABS * LDIM;  // colpart parity stride
  unsigned int* const cnt = counter + b * CNT_STRIDE;

  f4 ahv[3][2];
  float colacc[8];

  // __syncthreads() drains vmcnt per wave, so all waves' sc1 partial stores
  // are at the coherence point before tid0's counter add. Spin load is
  // RELAXED (sc1 loads always read fresh; no cache maintenance).
#define ARRIVE_WAIT(tgt)                                                       \
  do {                                                                         \
    __syncthreads();                                                           \
    if (tid == 0) {                                                            \
      __hip_atomic_fetch_add(cnt, 1u, __ATOMIC_RELEASE,                        \
                             __HIP_MEMORY_SCOPE_AGENT);                        \
      while (__hip_atomic_load(cnt, __ATOMIC_RELAXED,                          \
                               __HIP_MEMORY_SCOPE_AGENT) < (tgt))              \
        __builtin_amdgcn_s_sleep(8);                                           \
    }                                                                          \
    __syncthreads();                                                           \
  } while (0)

#define COLREDUCE_STORE(dstp)                                                  \
  do {                                                                         \
    if (w < 8) {                                                               \
      f4 sa = {colacc[0], colacc[1], colacc[2], colacc[3]};                    \
      f4 sbv = {colacc[4], colacc[5], colacc[6], colacc[7]};                   \
      *(f4*)&stage[w][j0] = sa;                                                \
      *(f4*)&stage[w][256 + j0] = sbv;                                         \
    }                                                                          \
    __syncthreads();                                                           \
    if (w >= 8) {                                                              \
      f4 sa = *(f4*)&stage[w - 8][j0];                                         \
      f4 sbv = *(f4*)&stage[w - 8][256 + j0];                                  \
      sa[0] += colacc[0]; sa[1] += colacc[1];                                  \
      sa[2] += colacc[2]; sa[3] += colacc[3];                                  \
      sbv[0] += colacc[4]; sbv[1] += colacc[5];                                \
      sbv[2] += colacc[6]; sbv[3] += colacc[7];                                \
      *(f4*)&stage[w - 8][j0] = sa;                                            \
      *(f4*)&stage[w - 8][256 + j0] = sbv;                                     \
    }                                                                          \
    __syncthreads();                                                           \
    if (tid < LDIM) {                                                          \
      float cs = stage[0][tid] + stage[1][tid] + stage[2][tid] +               \
                 stage[3][tid] + stage[4][tid] + stage[5][tid] +               \
                 stage[6][tid] + stage[7][tid];                                \
      st_agent((dstp) + tid, cs);                                              \
    }                                                                          \
  } while (0)

  // ---- P_init: A_hat_0 = scores into regs/LDS; partials of M .* A_hat_0 ----
#pragma unroll
  for (int k = 0; k < 8; k++) colacc[k] = 0.0f;
#pragma unroll
  for (int r = 0; r < 4; r++) {
    const int i = wrow + r;
    const size_t base = mb + (size_t)i * LDIM;
    const f4 s0 = *(const f4*)(scores + base + j0);
    const f4 s1 = *(const f4*)(scores + base + 256 + j0);
    const h4 m0 = *(const h4*)(MU + base + j0);
    const h4 m1 = *(const h4*)(MU + base + 256 + j0);
    if (r < 3) {
      ahv[r][0] = s0;
      ahv[r][1] = s1;
    } else {
      *(f4*)&ahL[w][j0] = s0;
      *(f4*)&ahL[w][256 + j0] = s1;
    }
    float rowc = 0.0f;
#pragma unroll
    for (int k = 0; k < 4; k++) {
      const float c0v = ((float)m0[k] > MU_THRESH) ? s0[k] : 0.0f;
      const float c1v = ((float)m1[k] > MU_THRESH) ? s1[k] : 0.0f;
      rowc += c0v + c1v;
      colacc[k] += c0v;
      colacc[4 + k] += c1v;
    }
    const float rsum = wave_reduce_sum(rowc);
    if (lane == 0) st_agent(rowpart + (size_t)b * LDIM + i, rsum);
  }
  COLREDUCE_STORE(colpart + ((size_t)b * SLABS + sb) * LDIM);
  ARRIVE_WAIT((unsigned)SLABS);

  // ---- 20 steps ----
  for (int sp = 0; sp < NSTEPS; ++sp) {
    const int par = sp & 1;
    // lm phase: identical on all 8 sibling blocks (bit-deterministic).
    if (tid < LDIM) {
      const int i = tid;
      const float rsum = ld_agent(rowpart + (size_t)par * RP + (size_t)b * LDIM + i);
      const float* cb = colpart + (size_t)par * CP + (size_t)b * SLABS * LDIM + i;
      float csum = 0.0f;
#pragma unroll
      for (int s2 = 0; s2 < SLABS; s2++) csum += ld_agent(cb + (size_t)s2 * LDIM);
      const float rd = 0.5f * (rsum + csum) - 1.0f;
      float lm;
      if (sp == 0)
        lm = wv * relu_f(rd);
      else
        lm = lm_reg + belt * lrbp * relu_f(rd);
      lm_reg = lm;
      lmsgS[i] = lm * sign_f(rd);
    }
    __syncthreads();

    const f4 lmja = *(const f4*)&lmsgS[j0];
    const f4 lmjb = *(const f4*)&lmsgS[256 + j0];
    const bool last = (sp == NSTEPS - 1);
    const float rat = at;
#pragma unroll
    for (int k = 0; k < 8; k++) colacc[k] = 0.0f;

    // VGPR-resident rows (0..2)
#pragma unroll
    for (int r = 0; r < 3; r++) {
      const int i = wrow + r;
      const size_t base = mb + (size_t)i * LDIM;
      const float lmi = lmsgS[i];
      const h4 mh0 = *(const h4*)(MU + base + j0);
      const h4 mh1 = *(const h4*)(MU + base + 256 + j0);
      const f4 rh0 = *(const f4*)(rho_p + (size_t)i * LDIM + j0);
      const f4 rh1 = *(const f4*)(rho_p + (size_t)i * LDIM + 256 + j0);
      float rowc = 0.0f;
#pragma unroll
      for (int k = 0; k < 4; k++) {
        const float mva = (float)mh0[k];
        const bool ma = mva > MU_THRESH;
        const float ga = ma ? (mva - lmi - lmja[k]) : 0.0f;
        const float ua = ahv[r][0][k] * fmaf(rat, ga, 1.0f);
        const float va = fminf(relu_f(fabsf(ua) - rh0[k] * rat), 1.0f);
        ahv[r][0][k] = va;
        const float ca = ma ? va : 0.0f;
        rowc += ca;
        colacc[k] += ca;
        const float mvb = (float)mh1[k];
        const bool mbk = mvb > MU_THRESH;
        const float gb = mbk ? (mvb - lmi - lmjb[k]) : 0.0f;
        const float ub = ahv[r][1][k] * fmaf(rat, gb, 1.0f);
        const float vb = fminf(relu_f(fabsf(ub) - rh1[k] * rat), 1.0f);
        ahv[r][1][k] = vb;
        const float cbv = mbk ? vb : 0.0f;
        rowc += cbv;
        colacc[4 + k] += cbv;
      }
      if (!last) {
        const float rsum = wave_reduce_sum(rowc);
        if (lane == 0)
          st_agent(rowpart + (size_t)(par ^ 1) * RP + (size_t)b * LDIM + i, rsum);
      }
    }
    // LDS-resident row (3)
    {
      const int i = wrow + 3;
      const size_t base = mb + (size_t)i * LDIM;
      const float lmi = lmsgS[i];
      const h4 mh0 = *(const h4*)(MU + base + j0);
      const h4 mh1 = *(const h4*)(MU + base + 256 + j0);
      const f4 rh0 = *(const f4*)(rho_p + (size_t)i * LDIM + j0);
      const f4 rh1 = *(const f4*)(rho_p + (size_t)i * LDIM + 256 + j0);
      f4 a0 = *(const f4*)&ahL[w][j0];
      f4 a1 = *(const f4*)&ahL[w][256 + j0];
      float rowc = 0.0f;
#pragma unroll
      for (int k = 0; k < 4; k++) {
        const float mva = (float)mh0[k];
        const bool ma = mva > MU_THRESH;
        const float ga = ma ? (mva - lmi - lmja[k]) : 0.0f;
        const float ua = a0[k] * fmaf(rat, ga, 1.0f);
        const float va = fminf(relu_f(fabsf(ua) - rh0[k] * rat), 1.0f);
        a0[k] = va;
        const float ca = ma ? va : 0.0f;
        rowc += ca;
        colacc[k] += ca;
        const float mvb = (float)mh1[k];
        const bool mbk = mvb > MU_THRESH;
        const float gb = mbk ? (mvb - lmi - lmjb[k]) : 0.0f;
        const float ub = a1[k] * fmaf(rat, gb, 1.0f);
        const float vb = fminf(relu_f(fabsf(ub) - rh1[k] * rat), 1.0f);
        a1[k] = vb;
        const float cbv = mbk ? vb : 0.0f;
        rowc += cbv;
        colacc[4 + k] += cbv;
      }
      *(f4*)&ahL[w][j0] = a0;
      *(f4*)&ahL[w][256 + j0] = a1;
      if (!last) {
        const float rsum = wave_reduce_sum(rowc);
        if (lane == 0)
          st_agent(rowpart + (size_t)(par ^ 1) * RP + (size_t)b * LDIM + i, rsum);
      }
    }
    if (!last) {
      COLREDUCE_STORE(colpart + (size_t)(par ^ 1) * CP + ((size_t)b * SLABS + sb) * LDIM);
      ARRIVE_WAIT((unsigned)SLABS * (unsigned)(sp + 2));
    }
    at *= lra;
    if (sp > 0) lrbp *= lrb;
  }

  // ---- write A_hat_20 out (k_final symmetrizes in place) ----
#pragma unroll
  for (int r = 0; r < 3; r++) {
    const size_t base = mb + (size_t)(wrow + r) * LDIM;
    *(f4*)(Ah + base + j0) = ahv[r][0];
    *(f4*)(Ah + base + 256 + j0) = ahv[r][1];
  }
  {
    const size_t base = mb + (size_t)(wrow + 3) * LDIM;
    *(f4*)(Ah + base + j0) = *(const f4*)&ahL[w][j0];
    *(f4*)(Ah + base + 256 + j0) = *(const f4*)&ahL[w][256 + j0];
  }
#undef ARRIVE_WAIT
#undef COLREDUCE_STORE
}

// ---------------------------------------------------------------------------
// K_final: in-place A = 0.5*(Ah + Ah^T) .* M over tile pairs (64x64 tiles).
// ---------------------------------------------------------------------------
__global__ __launch_bounds__(NTHREADS) void k_final(float* __restrict__ Ah,
                                                    const float* __restrict__ M) {
  __shared__ float At[64][65];
  __shared__ float Bt[64][65];
  const int b = blockIdx.x / 36;
  int rem = blockIdx.x % 36;
  int ti = 0;
  while (rem >= 8 - ti) {
    rem -= 8 - ti;
    ti++;
  }
  const int tj = ti + rem;
  const int tid = threadIdx.x;
  const int c = tid & 63;
  const int r0 = tid >> 6;
  const size_t mb = (size_t)b * LDIM * LDIM;

#pragma unroll
  for (int k = 0; k < 16; k++) {
    const int r = 4 * k + r0;
    At[r][c] = Ah[mb + (size_t)(ti * 64 + r) * LDIM + tj * 64 + c];
    Bt[r][c] = Ah[mb + (size_t)(tj * 64 + r) * LDIM + ti * 64 + c];
  }
  __syncthreads();
#pragma unroll
  for (int k = 0; k < 16; k++) {
    const int r = 4 * k + r0;
    const size_t idx_ij = mb + (size_t)(ti * 64 + r) * LDIM + tj * 64 + c;
    const float mij = M[idx_ij];
    Ah[idx_ij] = 0.5f * (At[r][c] + Bt[c][r]) * mij;
    if (ti != tj) {
      const size_t idx_ji = mb + (size_t)(tj * 64 + r) * LDIM + ti * 64 + c;
      const float mji = M[idx_ji];
      Ah[idx_ji] = 0.5f * (Bt[r][c] + At[c][r]) * mji;
    }
  }
}

// ---------------------------------------------------------------------------
extern "C" void kernel_launch(void* const* d_in, const int* in_sizes, int n_in,
                              void* d_out, int out_size, void* d_ws,
                              size_t ws_size, hipStream_t stream) {
  const float* scores = (const float*)d_in[0];
  const float* M = (const float*)d_in[1];
  const float* s_p = (const float*)d_in[2];
  const float* w_p = (const float*)d_in[3];
  const float* rho = (const float*)d_in[4];
  const float* alpha_p = (const float*)d_in[5];
  const float* belt_p = (const float*)d_in[6];
  const float* lra_p = (const float*)d_in[7];
  const float* lrb_p = (const float*)d_in[8];
  float* Ah = (float*)d_out;

  char* ws = (char*)d_ws;
  size_t off = 0;
  auto walloc = [&](size_t bytes) -> void* {
    void* p = (void*)(ws + off);
    off += (bytes + 255) & ~(size_t)255;
    return p;
  };
  const size_t NEL = (size_t)BATCH * LDIM * LDIM;
  _Float16* MU = (_Float16*)walloc(NEL * 2);                             // 32 MB
  float* rowpart = (float*)walloc((size_t)2 * BATCH * LDIM * 4);         // 256 KB
  float* colpart = (float*)walloc((size_t)2 * BATCH * SLABS * LDIM * 4); // 2 MB
  unsigned int* cnt = (unsigned int*)walloc(BATCH * CNT_STRIDE * 4);     // 4 KB
  (void)in_sizes;
  (void)n_in;
  (void)out_size;
  (void)ws_size;

  k_build<<<dim3(BATCH * 36), dim3(NTHREADS), 0, stream>>>(scores, M, s_p, MU,
                                                           cnt);

  // Plain launch (no cooperative: it measured ~175 us/replay of overhead).
  // Grid = BATCH*SLABS = 512 blocks = exact capacity at 2 blocks/CU
  // (50 KB LDS, 64 VGPR enforced by amdgpu_waves_per_eu(8)).
  k_persist<<<dim3(BATCH * SLABS), dim3(PTHREADS), 0, stream>>>(
      scores, MU, rho, w_p, alpha_p, belt_p, lra_p, lrb_p, rowpart, colpart,
      cnt, Ah);

  k_final<<<dim3(BATCH * 36), dim3(NTHREADS), 0, stream>>>(Ah, M);
}

// Round 9
// 543.192 us; speedup vs baseline: 2.5002x; 2.5002x over previous
//
#include <hip/hip_runtime.h>
#include <cstdint>
#include <cstddef>

// Problem constants (match reference: B=64, L=512, STEPS=20)
#define LDIM 512
#define BATCH 64
#define NSTEPS 20
#define NTHREADS 256
#define PTHREADS 1024
#define SLABS 4        // row slabs per batch (128 rows each)
#define HALVES 2       // column halves (256 cols each)
#define BPB 8          // blocks per batch = SLABS*HALVES
#define CNT_STRIDE 16  // 64 B per counter: no line sharing across batches

using f4 = __attribute__((ext_vector_type(4))) float;
using h4 = __attribute__((ext_vector_type(4))) _Float16;

#define MU_MASKED (-1024.0f)   // exact in fp16; sentinel for M==0
#define MU_THRESH (-512.0f)

__device__ __forceinline__ float relu_f(float x) { return fmaxf(x, 0.0f); }
__device__ __forceinline__ float sign_f(float x) {
  return (x > 0.0f) ? 1.0f : ((x < 0.0f) ? -1.0f : 0.0f);
}
__device__ __forceinline__ float wave_reduce_sum(float v) {
  v += __shfl_xor(v, 32);
  v += __shfl_xor(v, 16);
  v += __shfl_xor(v, 8);
  v += __shfl_xor(v, 4);
  v += __shfl_xor(v, 2);
  v += __shfl_xor(v, 1);
  return v;
}
// Agent-scope RELAXED accesses: sc1 ops serviced at the coherence point.
// Never acquire/threadfence (agent-acquire = full per-XCD L2 invalidate;
// round-1 spent 97% of its time there).
__device__ __forceinline__ void st_agent(float* p, float v) {
  __hip_atomic_store(p, v, __ATOMIC_RELAXED, __HIP_MEMORY_SCOPE_AGENT);
}
__device__ __forceinline__ float ld_agent(const float* p) {
  return __hip_atomic_load(p, __ATOMIC_RELAXED, __HIP_MEMORY_SCOPE_AGENT);
}

// ---------------------------------------------------------------------------
// k_build: MU[b][i][j] = M_ij ? fp16(0.5*(sc_ij + sc_ji) - s) : -1024, via
// 64x64 tile pairs (coalesced transpose through LDS). Also zeroes the
// per-batch sync counters. Grid: BATCH * 36 tile pairs; 256 threads.
// ---------------------------------------------------------------------------
__global__ __launch_bounds__(NTHREADS) void k_build(
    const float* __restrict__ scores, const float* __restrict__ M,
    const float* __restrict__ s_ptr, _Float16* __restrict__ MU,
    unsigned int* __restrict__ counter) {
  __shared__ float Sa[64][65];
  __shared__ float Sb[64][65];
  if (blockIdx.x < BATCH && threadIdx.x == 0) counter[blockIdx.x * CNT_STRIDE] = 0u;
  const int b = blockIdx.x / 36;
  int rem = blockIdx.x % 36;
  int ti = 0;
  while (rem >= 8 - ti) {
    rem -= 8 - ti;
    ti++;
  }
  const int tj = ti + rem;
  const int tid = threadIdx.x;
  const int c = tid & 63;
  const int r0 = tid >> 6;
  const float sval = s_ptr[0];
  const size_t mb = (size_t)b * LDIM * LDIM;
#pragma unroll
  for (int k = 0; k < 16; k++) {
    const int r = 4 * k + r0;
    Sa[r][c] = scores[mb + (size_t)(ti * 64 + r) * LDIM + tj * 64 + c];
    Sb[r][c] = scores[mb + (size_t)(tj * 64 + r) * LDIM + ti * 64 + c];
  }
  __syncthreads();
#pragma unroll
  for (int k = 0; k < 16; k++) {
    const int r = 4 * k + r0;
    const size_t idx_ij = mb + (size_t)(ti * 64 + r) * LDIM + tj * 64 + c;
    const float mij = M[idx_ij];
    const float us = 0.5f * (Sa[r][c] + Sb[c][r]) - sval;
    MU[idx_ij] = (_Float16)((mij != 0.0f) ? us : MU_MASKED);
    if (ti != tj) {
      const size_t idx_ji = mb + (size_t)(tj * 64 + r) * LDIM + ti * 64 + c;
      const float mji = M[idx_ji];
      const float usj = 0.5f * (Sb[r][c] + Sa[c][r]) - sval;
      MU[idx_ji] = (_Float16)((mji != 0.0f) ? usj : MU_MASKED);
    }
  }
}

// ---------------------------------------------------------------------------
// k_rho: rho fp32 -> fp16 (0.5 MB, L2-resident for the step loop).
// Precision: rho in [0,1); fp16 abs err <= ~5e-4; enters only as the
// soft-threshold rho*a_t (a_t <= 0.005) -> <=2.5e-6/step, negligible.
// ---------------------------------------------------------------------------
__global__ __launch_bounds__(NTHREADS) void k_rho(const float* __restrict__ rho,
                                                  _Float16* __restrict__ rho_h) {
  const int idx = (blockIdx.x * NTHREADS + threadIdx.x) * 4;
  const f4 v = *(const f4*)(rho + idx);
  h4 o;
#pragma unroll
  for (int k = 0; k < 4; k++) o[k] = (_Float16)v[k];
  *(h4*)(rho_h + idx) = o;
}

// ---------------------------------------------------------------------------
// k_persist: COLUMN-SPLIT so all step-invariant data is on-chip.
// Block = (batch b, row-slab sb of 128 rows, col-half hf of 256 cols);
// blockIdx = b*8 + sb*2 + hf (adjacent siblings). Launched COOPERATIVELY
// (guaranteed co-residency of all 512 blocks) with plain-launch fallback
// (round-6-proven: 512 blocks, 8-per-batch spin sync, completed fine).
// Grid 512 x 1024 thr = 2 blocks/CU target, 32 waves/CU.
// Per thread: 8 rows x 4 cols of A_hat ENTIRELY in VGPRs (32 regs — fits the
// empirical 64-VGPR allocation this toolchain pins for 1024-thr blocks;
// rounds 3/4/6 proved bigger state or waves_per_eu attrs -> spill).
// Per block LDS: MU fp16 [128][256] = 64 KB RESIDENT (loaded once) +
// stage 8 KB + lmsg 2 KB = 74 KB -> 2 blocks/CU. rho fp16 streams from L2.
// => ZERO bulk global traffic inside the step loop.
// Cross-block: partials via sc1 relaxed atomics + per-batch monotonic
// arrival counter (8 arrivals/step). NO fences, NO acquire.
// ---------------------------------------------------------------------------
__global__ __launch_bounds__(PTHREADS, 4) void k_persist(
    const float* __restrict__ scores, const _Float16* __restrict__ MU,
    const _Float16* __restrict__ rho_h, const float* __restrict__ w_ptr,
    const float* __restrict__ alpha_ptr, const float* __restrict__ belt_ptr,
    const float* __restrict__ lra_ptr, const float* __restrict__ lrb_ptr,
    float* __restrict__ rowpart, float* __restrict__ colpart,
    unsigned int* __restrict__ counter, float* __restrict__ Ah) {
  __shared__ _Float16 muL[128][256];  // 64 KB: resident masked usym tile
  __shared__ float stage[8][256];     // 8 KB: cross-wave col-sum staging
  __shared__ float lmsgS[LDIM];       // 2 KB  (total 74 KB -> 2 blocks/CU)

  const int tid = threadIdx.x;
  const int lane = tid & 63;
  const int w = tid >> 6;               // 0..15
  const int b = blockIdx.x >> 3;        // batch
  const int s = blockIdx.x & 7;
  const int sb = s >> 1;                // row slab 0..3
  const int hf = s & 1;                 // col half 0..1
  const int wrow = sb * 128 + w * 8;    // global first row of this wave
  const int j0 = lane << 2;             // local col 0..255 (step 4)
  const int gj0 = hf * 256 + j0;        // global col
  const size_t mb = (size_t)b * LDIM * LDIM;

  const float wv = w_ptr[0];
  const float belt = belt_ptr[0];
  const float lra = lra_ptr[0];
  const float lrb = lrb_ptr[0];
  float at = alpha_ptr[0];  // a_t = alpha * lra^sp
  float lrbp = 1.0f;        // lrb^(sp-1) for sp>=1
  float lm_reg = 0.0f;      // Lm[tid] (valid for tid < LDIM)

  const size_t RP = (size_t)BATCH * HALVES * LDIM;  // rowpart parity stride
  const size_t CP = (size_t)BATCH * SLABS * LDIM;   // colpart parity stride
  unsigned int* const cnt = counter + b * CNT_STRIDE;

  f4 ahv[8];
  float colacc[4];

  // __syncthreads() drains vmcnt per wave -> all sc1 partial stores are at
  // the coherence point before tid0's counter add. Spin load RELAXED.
#define ARRIVE_WAIT(tgt)                                                       \
  do {                                                                         \
    __syncthreads();                                                           \
    if (tid == 0) {                                                            \
      __hip_atomic_fetch_add(cnt, 1u, __ATOMIC_RELEASE,                        \
                             __HIP_MEMORY_SCOPE_AGENT);                        \
      while (__hip_atomic_load(cnt, __ATOMIC_RELAXED,                          \
                               __HIP_MEMORY_SCOPE_AGENT) < (tgt))              \
        __builtin_amdgcn_s_sleep(8);                                           \
    }                                                                          \
    __syncthreads();                                                           \
  } while (0)

#define COLREDUCE_STORE(dstp)                                                  \
  do {                                                                         \
    if (w < 8) {                                                               \
      f4 sa = {colacc[0], colacc[1], colacc[2], colacc[3]};                    \
      *(f4*)&stage[w][j0] = sa;                                                \
    }                                                                          \
    __syncthreads();                                                           \
    if (w >= 8) {                                                              \
      f4 sa = *(f4*)&stage[w - 8][j0];                                         \
      sa[0] += colacc[0]; sa[1] += colacc[1];                                  \
      sa[2] += colacc[2]; sa[3] += colacc[3];                                  \
      *(f4*)&stage[w - 8][j0] = sa;                                            \
    }                                                                          \
    __syncthreads();                                                           \
    if (tid < 256) {                                                           \
      float cs = stage[0][tid] + stage[1][tid] + stage[2][tid] +               \
                 stage[3][tid] + stage[4][tid] + stage[5][tid] +               \
                 stage[6][tid] + stage[7][tid];                                \
      st_agent((dstp) + tid, cs);                                              \
    }                                                                          \
  } while (0)

  // ---- P_init: A_hat_0 = scores into VGPRs; MU(fp16) into LDS; partials ----
#pragma unroll
  for (int k = 0; k < 4; k++) colacc[k] = 0.0f;
#pragma unroll
  for (int r = 0; r < 8; r++) {
    const int i = wrow + r;
    const size_t base = mb + (size_t)i * LDIM + gj0;
    const f4 s0 = *(const f4*)(scores + base);
    const h4 m0 = *(const h4*)(MU + base);
    ahv[r] = s0;
    *(h4*)&muL[(w << 3) + r][j0] = m0;
    float rowc = 0.0f;
#pragma unroll
    for (int k = 0; k < 4; k++) {
      const float c0v = ((float)m0[k] > MU_THRESH) ? s0[k] : 0.0f;
      rowc += c0v;
      colacc[k] += c0v;
    }
    const float rhalf = wave_reduce_sum(rowc);
    if (lane == 0)
      st_agent(rowpart + ((size_t)b * HALVES + hf) * LDIM + i, rhalf);
  }
  COLREDUCE_STORE(colpart + ((size_t)b * SLABS + sb) * LDIM + hf * 256);
  ARRIVE_WAIT((unsigned)BPB);

  // ---- 20 steps ----
  for (int sp = 0; sp < NSTEPS; ++sp) {
    const int par = sp & 1;
    // lm phase: identical on all 8 sibling blocks (bit-deterministic).
    if (tid < LDIM) {
      const int i = tid;
      const float rsum =
          ld_agent(rowpart + (size_t)par * RP + ((size_t)b * HALVES + 0) * LDIM + i) +
          ld_agent(rowpart + (size_t)par * RP + ((size_t)b * HALVES + 1) * LDIM + i);
      const float* cb = colpart + (size_t)par * CP + (size_t)b * SLABS * LDIM + i;
      const float csum = ld_agent(cb) + ld_agent(cb + LDIM) +
                         ld_agent(cb + 2 * LDIM) + ld_agent(cb + 3 * LDIM);
      const float rd = 0.5f * (rsum + csum) - 1.0f;
      float lm;
      if (sp == 0)
        lm = wv * relu_f(rd);
      else
        lm = lm_reg + belt * lrbp * relu_f(rd);
      lm_reg = lm;
      lmsgS[i] = lm * sign_f(rd);
    }
    __syncthreads();

    const f4 lmja = *(const f4*)&lmsgS[gj0];
    const bool last = (sp == NSTEPS - 1);
    const float rat = at;
#pragma unroll
    for (int k = 0; k < 4; k++) colacc[k] = 0.0f;

#pragma unroll
    for (int r = 0; r < 8; r++) {
      const int i = wrow + r;
      const int lr = (w << 3) + r;
      const float lmi = lmsgS[i];
      const h4 mh = *(const h4*)&muL[lr][j0];
      const h4 rh = *(const h4*)(rho_h + (size_t)i * LDIM + gj0);
      float rowc = 0.0f;
#pragma unroll
      for (int k = 0; k < 4; k++) {
        const float mv = (float)mh[k];
        const bool ma = mv > MU_THRESH;
        const float g = ma ? (mv - lmi - lmja[k]) : 0.0f;
        const float u = ahv[r][k] * fmaf(rat, g, 1.0f);
        const float v = fminf(relu_f(fabsf(u) - (float)rh[k] * rat), 1.0f);
        ahv[r][k] = v;
        const float c = ma ? v : 0.0f;
        rowc += c;
        colacc[k] += c;
      }
      if (!last) {
        const float rhalf = wave_reduce_sum(rowc);
        if (lane == 0)
          st_agent(rowpart + (size_t)(par ^ 1) * RP +
                       ((size_t)b * HALVES + hf) * LDIM + i,
                   rhalf);
      }
    }
    if (!last) {
      COLREDUCE_STORE(colpart + (size_t)(par ^ 1) * CP +
                      ((size_t)b * SLABS + sb) * LDIM + hf * 256);
      ARRIVE_WAIT((unsigned)BPB * (unsigned)(sp + 2));
    }
    at *= lra;
    if (sp > 0) lrbp *= lrb;
  }

  // ---- write A_hat_20 out (k_final symmetrizes in place) ----
#pragma unroll
  for (int r = 0; r < 8; r++) {
    const size_t base = mb + (size_t)(wrow + r) * LDIM + gj0;
    *(f4*)(Ah + base) = ahv[r];
  }
#undef ARRIVE_WAIT
#undef COLREDUCE_STORE
}

// ---------------------------------------------------------------------------
// K_final: in-place A = 0.5*(Ah + Ah^T) .* M over tile pairs (64x64 tiles).
// ---------------------------------------------------------------------------
__global__ __launch_bounds__(NTHREADS) void k_final(float* __restrict__ Ah,
                                                    const float* __restrict__ M) {
  __shared__ float At[64][65];
  __shared__ float Bt[64][65];
  const int b = blockIdx.x / 36;
  int rem = blockIdx.x % 36;
  int ti = 0;
  while (rem >= 8 - ti) {
    rem -= 8 - ti;
    ti++;
  }
  const int tj = ti + rem;
  const int tid = threadIdx.x;
  const int c = tid & 63;
  const int r0 = tid >> 6;
  const size_t mb = (size_t)b * LDIM * LDIM;

#pragma unroll
  for (int k = 0; k < 16; k++) {
    const int r = 4 * k + r0;
    At[r][c] = Ah[mb + (size_t)(ti * 64 + r) * LDIM + tj * 64 + c];
    Bt[r][c] = Ah[mb + (size_t)(tj * 64 + r) * LDIM + ti * 64 + c];
  }
  __syncthreads();
#pragma unroll
  for (int k = 0; k < 16; k++) {
    const int r = 4 * k + r0;
    const size_t idx_ij = mb + (size_t)(ti * 64 + r) * LDIM + tj * 64 + c;
    const float mij = M[idx_ij];
    Ah[idx_ij] = 0.5f * (At[r][c] + Bt[c][r]) * mij;
    if (ti != tj) {
      const size_t idx_ji = mb + (size_t)(tj * 64 + r) * LDIM + ti * 64 + c;
      const float mji = M[idx_ji];
      Ah[idx_ji] = 0.5f * (Bt[r][c] + At[c][r]) * mji;
    }
  }
}

// ---------------------------------------------------------------------------
extern "C" void kernel_launch(void* const* d_in, const int* in_sizes, int n_in,
                              void* d_out, int out_size, void* d_ws,
                              size_t ws_size, hipStream_t stream) {
  const float* scores = (const float*)d_in[0];
  const float* M = (const float*)d_in[1];
  const float* s_p = (const float*)d_in[2];
  const float* w_p = (const float*)d_in[3];
  const float* rho = (const float*)d_in[4];
  const float* alpha_p = (const float*)d_in[5];
  const float* belt_p = (const float*)d_in[6];
  const float* lra_p = (const float*)d_in[7];
  const float* lrb_p = (const float*)d_in[8];
  float* Ah = (float*)d_out;

  char* ws = (char*)d_ws;
  size_t off = 0;
  auto walloc = [&](size_t bytes) -> void* {
    void* p = (void*)(ws + off);
    off += (bytes + 255) & ~(size_t)255;
    return p;
  };
  const size_t NEL = (size_t)BATCH * LDIM * LDIM;
  _Float16* MU = (_Float16*)walloc(NEL * 2);                               // 32 MB
  _Float16* rho_h = (_Float16*)walloc((size_t)LDIM * LDIM * 2);            // 0.5 MB
  float* rowpart = (float*)walloc((size_t)2 * BATCH * HALVES * LDIM * 4);  // 512 KB
  float* colpart = (float*)walloc((size_t)2 * BATCH * SLABS * LDIM * 4);   // 1 MB
  unsigned int* cnt = (unsigned int*)walloc(BATCH * CNT_STRIDE * 4);       // 4 KB
  (void)in_sizes;
  (void)n_in;
  (void)out_size;
  (void)ws_size;

  k_build<<<dim3(BATCH * 36), dim3(NTHREADS), 0, stream>>>(scores, M, s_p, MU,
                                                           cnt);
  k_rho<<<dim3(LDIM * LDIM / (NTHREADS * 4)), dim3(NTHREADS), 0, stream>>>(
      rho, rho_h);

  // Cooperative launch first: GUARANTEES all 512 blocks co-resident (the
  // only way the spin sync can be starved is partial residency). Fallback:
  // plain launch — the round-6-proven configuration (512 blocks, adjacent
  // 8-per-batch numbering, drain-safe at any occupancy).
  void* args[] = {(void*)&scores,  (void*)&MU,      (void*)&rho_h,
                  (void*)&w_p,     (void*)&alpha_p, (void*)&belt_p,
                  (void*)&lra_p,   (void*)&lrb_p,   (void*)&rowpart,
                  (void*)&colpart, (void*)&cnt,     (void*)&Ah};
  hipError_t cerr = hipLaunchCooperativeKernel(
      (const void*)k_persist, dim3(BATCH * BPB), dim3(PTHREADS), args, 0,
      stream);
  if (cerr != hipSuccess) {
    k_persist<<<dim3(BATCH * BPB), dim3(PTHREADS), 0, stream>>>(
        scores, MU, rho_h, w_p, alpha_p, belt_p, lra_p, lrb_p, rowpart,
        colpart, cnt, Ah);
  }

  k_final<<<dim3(BATCH * 36), dim3(NTHREADS), 0, stream>>>(Ah, M);
}